// Round 1
// baseline (268.145 us; speedup 1.0000x reference)
//
#include <hip/hip_runtime.h>
#include <stdint.h>

typedef __bf16 bf16x8 __attribute__((ext_vector_type(8)));
typedef float floatx4 __attribute__((ext_vector_type(4)));
typedef unsigned short ushort_t;

#define LDE 40    // row stride (elems) for 32-wide K tiles, padded (+8) to break bank conflicts
#define LDH 136   // row stride for sH1 [row][128 h], padded (+8)

__device__ __forceinline__ ushort_t bf16rne(float f) {
    union { float f; unsigned u; } v; v.f = f;
    return (ushort_t)((v.u + 0x7fffu + ((v.u >> 16) & 1u)) >> 16);
}
__device__ __forceinline__ float bf16tof(ushort_t s) {
    union { unsigned u; float f; } v; v.u = ((unsigned)s) << 16;
    return v.f;
}

// ---------------- fp32 -> bf16 straight convert (x) ----------------
__global__ void convert_bf16(const float* __restrict__ in, ushort_t* __restrict__ outp, int n4) {
    int i = blockIdx.x * 256 + threadIdx.x;
    if (i >= n4) return;
    float4 f = ((const float4*)in)[i];
    union { ushort_t s[4]; uint2 v; } pk;
    pk.s[0] = bf16rne(f.x); pk.s[1] = bf16rne(f.y);
    pk.s[2] = bf16rne(f.z); pk.s[3] = bf16rne(f.w);
    ((uint2*)outp)[i] = pk.v;
}

// ------------- fp32 [e][K][N] -> bf16 [e][N][K] transpose ----------
__global__ void transpose_bf16(const float* __restrict__ in, ushort_t* __restrict__ outp,
                               int K, int N, int total) {
    int idx = blockIdx.x * 256 + threadIdx.x;
    if (idx >= total) return;
    int kn = K * N;
    int e = idx / kn;
    int r = idx - e * kn;
    int n = r / K;
    int k = r - n * K;
    outp[idx] = bf16rne(in[e * kn + k * N + n]);
}

// ---------------- generic transposed-MFMA GEMM + relu --------------
// out[row][nb*128+n] = relu( sum_k act[row][k] * w[k][n] + bias[n] ), w given as wT[n][k]
__global__ __launch_bounds__(256, 2)
void gemm_rt(const ushort_t* __restrict__ act, const ushort_t* __restrict__ wT,
             const float* __restrict__ bias, ushort_t* __restrict__ outp,
             int K, int N) {
    __shared__ ushort_t sA[128 * LDE];   // wT tile  [n][k]
    __shared__ ushort_t sB[128 * LDE];   // act tile [row][k]
    __shared__ float sBias[128];

    const int tid = threadIdx.x;
    const int rb = blockIdx.x, nb = blockIdx.y;
    const int wave = tid >> 6, lane = tid & 63;
    const int ln15 = lane & 15, q = lane >> 4;
    const int wm = (wave & 1) * 64;   // n dim
    const int wn = (wave >> 1) * 64;  // row dim

    if (tid < 128) sBias[tid] = bias[nb * 128 + tid];

    const ushort_t* arow = act + (size_t)rb * 128 * K;
    const ushort_t* wrow = wT + (size_t)nb * 128 * K;

    floatx4 acc[4][4];
#pragma unroll
    for (int i = 0; i < 4; ++i)
#pragma unroll
        for (int j = 0; j < 4; ++j) acc[i][j] = (floatx4){0.f, 0.f, 0.f, 0.f};

    for (int k0 = 0; k0 < K; k0 += 32) {
        __syncthreads();
#pragma unroll
        for (int p = 0; p < 2; ++p) {
            int v = tid + p * 256;
            int row = v >> 2, c8 = (v & 3) * 8;
            *(uint4*)(&sA[row * LDE + c8]) = *(const uint4*)(&wrow[(size_t)row * K + k0 + c8]);
            *(uint4*)(&sB[row * LDE + c8]) = *(const uint4*)(&arow[(size_t)row * K + k0 + c8]);
        }
        __syncthreads();
        bf16x8 a[4], b[4];
#pragma unroll
        for (int t = 0; t < 4; ++t) a[t] = *(const bf16x8*)(&sA[(wm + t * 16 + ln15) * LDE + q * 8]);
#pragma unroll
        for (int t = 0; t < 4; ++t) b[t] = *(const bf16x8*)(&sB[(wn + t * 16 + ln15) * LDE + q * 8]);
#pragma unroll
        for (int i = 0; i < 4; ++i)
#pragma unroll
            for (int j = 0; j < 4; ++j)
                acc[i][j] = __builtin_amdgcn_mfma_f32_16x16x32_bf16(a[i], b[j], acc[i][j], 0, 0, 0);
    }

    // epilogue: D[m=n][col=row] ; m = wm+16i+4q+r, col = wn+16j+ln15
    const int rbase = rb * 128;
#pragma unroll
    for (int i = 0; i < 4; ++i) {
        int n0 = wm + i * 16 + q * 4;
#pragma unroll
        for (int j = 0; j < 4; ++j) {
            int row = wn + j * 16 + ln15;
            union { ushort_t s[4]; uint2 v; } pk;
#pragma unroll
            for (int r = 0; r < 4; ++r)
                pk.s[r] = bf16rne(fmaxf(acc[i][j][r] + sBias[n0 + r], 0.f));
            *(uint2*)(&outp[(size_t)(rbase + row) * N + nb * 128 + n0]) = pk.v;
        }
    }
}

// ---------------- router tail: logits + gumbel softmax -------------
__global__ void router_tail(const ushort_t* __restrict__ hr2, const float* __restrict__ rw3,
                            const float* __restrict__ rb3, const float* __restrict__ u,
                            float* __restrict__ wout) {
    __shared__ float sw3[1280];
    const int tid = threadIdx.x;
    for (int i = tid; i < 1280; i += 256) sw3[i] = rw3[i];
    __syncthreads();
    const int row = blockIdx.x * 256 + tid;
    float logit[10];
#pragma unroll
    for (int e = 0; e < 10; ++e) logit[e] = rb3[e];
    const ushort_t* hrow = hr2 + (size_t)row * 128;
    for (int o8 = 0; o8 < 128; o8 += 8) {
        uint4 pk = *(const uint4*)(&hrow[o8]);
        const ushort_t* hs = (const ushort_t*)&pk;
#pragma unroll
        for (int jj = 0; jj < 8; ++jj) {
            float hv = bf16tof(hs[jj]);
#pragma unroll
            for (int e = 0; e < 10; ++e) logit[e] += hv * sw3[(o8 + jj) * 10 + e];
        }
    }
    float v[10], mx = -1e30f;
#pragma unroll
    for (int e = 0; e < 10; ++e) {
        float uu = u[(size_t)row * 10 + e];
        uu = fminf(fmaxf(uu, 1e-10f), 1.0f);
        float g = -logf(-logf(uu) + 1e-10f);
        v[e] = (logit[e] + g) * (1.0f / 3.0f);
        mx = fmaxf(mx, v[e]);
    }
    float s = 0.f;
#pragma unroll
    for (int e = 0; e < 10; ++e) { v[e] = expf(v[e] - mx); s += v[e]; }
    float inv = 1.0f / s;
#pragma unroll
    for (int e = 0; e < 10; ++e) wout[(size_t)row * 10 + e] = v[e] * inv;
}

// --------- fused expert stack: relu(x@W1) -> relu(@W2) -> @W3 ------
__global__ __launch_bounds__(256, 2)
void expert_fused(const ushort_t* __restrict__ x16, const ushort_t* __restrict__ ew1t,
                  const ushort_t* __restrict__ ew2t, const float* __restrict__ eb1,
                  const float* __restrict__ eb2, const float* __restrict__ ew3,
                  const float* __restrict__ eb3, float* __restrict__ chart) {
    __shared__ ushort_t sX[128 * LDE];
    __shared__ ushort_t sW[128 * LDE];    // W1 chunk, later W2 chunk
    __shared__ ushort_t sH1[128 * LDH];   // h1 [row][h] bf16
    __shared__ float sB1[128];
    __shared__ float sB2[128];
    __shared__ float sW3[256];
    __shared__ float zbuf[128][2];

    const int tid = threadIdx.x;
    const int e = blockIdx.x % 10;
    const int rb = blockIdx.x / 10;
    const int wave = tid >> 6, lane = tid & 63;
    const int ln15 = lane & 15, q = lane >> 4;
    const int wm = (wave & 1) * 64;   // h / o dim
    const int wn = (wave >> 1) * 64;  // row dim

    if (tid < 128) sB1[tid] = eb1[e * 128 + tid];
    else sB2[tid - 128] = eb2[e * 128 + (tid - 128)];
    sW3[tid] = ew3[e * 256 + tid];

    const ushort_t* xblk = x16 + (size_t)rb * 128 * 512;
    const ushort_t* w1 = ew1t + (size_t)e * 128 * 512;

    // ---- GEMM1: h1^T = W1^T · x^T  (D[h][row]) ----
    {
        floatx4 acc[4][4];
#pragma unroll
        for (int i = 0; i < 4; ++i)
#pragma unroll
            for (int j = 0; j < 4; ++j) acc[i][j] = (floatx4){0.f, 0.f, 0.f, 0.f};

        for (int k0 = 0; k0 < 512; k0 += 32) {
            __syncthreads();
#pragma unroll
            for (int p = 0; p < 2; ++p) {
                int v = tid + p * 256;
                int row = v >> 2, c8 = (v & 3) * 8;
                *(uint4*)(&sX[row * LDE + c8]) = *(const uint4*)(&xblk[(size_t)row * 512 + k0 + c8]);
                *(uint4*)(&sW[row * LDE + c8]) = *(const uint4*)(&w1[(size_t)row * 512 + k0 + c8]);
            }
            __syncthreads();
            bf16x8 a[4], b[4];
#pragma unroll
            for (int t = 0; t < 4; ++t) a[t] = *(const bf16x8*)(&sW[(wm + t * 16 + ln15) * LDE + q * 8]);
#pragma unroll
            for (int t = 0; t < 4; ++t) b[t] = *(const bf16x8*)(&sX[(wn + t * 16 + ln15) * LDE + q * 8]);
#pragma unroll
            for (int i = 0; i < 4; ++i)
#pragma unroll
                for (int j = 0; j < 4; ++j)
                    acc[i][j] = __builtin_amdgcn_mfma_f32_16x16x32_bf16(a[i], b[j], acc[i][j], 0, 0, 0);
        }

        // relu(+bias) -> sH1[row][h]; C/D: m=h=wm+16i+4q+r, col=row=wn+16j+ln15
#pragma unroll
        for (int i = 0; i < 4; ++i) {
            int h0 = wm + i * 16 + q * 4;
#pragma unroll
            for (int j = 0; j < 4; ++j) {
                int row = wn + j * 16 + ln15;
                union { ushort_t s[4]; uint2 v; } pk;
#pragma unroll
                for (int r = 0; r < 4; ++r)
                    pk.s[r] = bf16rne(fmaxf(acc[i][j][r] + sB1[h0 + r], 0.f));
                *(uint2*)(&sH1[row * LDH + h0]) = pk.v;
            }
        }
    }

    // ---- GEMM2: h2^T = W2^T · h1^T  (D[o][row]) ----
    floatx4 acc2[4][4];
#pragma unroll
    for (int i = 0; i < 4; ++i)
#pragma unroll
        for (int j = 0; j < 4; ++j) acc2[i][j] = (floatx4){0.f, 0.f, 0.f, 0.f};

    const ushort_t* w2 = ew2t + (size_t)e * 128 * 128;
    for (int k0 = 0; k0 < 128; k0 += 32) {
        __syncthreads();   // guards sH1 writes->reads (1st iter) and sW reuse
#pragma unroll
        for (int p = 0; p < 2; ++p) {
            int v = tid + p * 256;
            int row = v >> 2, c8 = (v & 3) * 8;
            *(uint4*)(&sW[row * LDE + c8]) = *(const uint4*)(&w2[(size_t)row * 128 + k0 + c8]);
        }
        __syncthreads();
        bf16x8 a[4], b[4];
#pragma unroll
        for (int t = 0; t < 4; ++t) a[t] = *(const bf16x8*)(&sW[(wm + t * 16 + ln15) * LDE + q * 8]);
#pragma unroll
        for (int t = 0; t < 4; ++t) b[t] = *(const bf16x8*)(&sH1[(wn + t * 16 + ln15) * LDH + k0 + q * 8]);
#pragma unroll
        for (int i = 0; i < 4; ++i)
#pragma unroll
            for (int j = 0; j < 4; ++j)
                acc2[i][j] = __builtin_amdgcn_mfma_f32_16x16x32_bf16(a[i], b[j], acc2[i][j], 0, 0, 0);
    }

    // ---- fused GEMM3 (L=2) in registers: zc[row][l] = sum_o relu(h2)*w3[o][l] ----
    float zc0[4] = {0.f, 0.f, 0.f, 0.f}, zc1[4] = {0.f, 0.f, 0.f, 0.f};
#pragma unroll
    for (int i = 0; i < 4; ++i) {
        int o0 = wm + i * 16 + q * 4;
#pragma unroll
        for (int r = 0; r < 4; ++r) {
            int o = o0 + r;
            float w3a = sW3[2 * o], w3b = sW3[2 * o + 1];
            float bias = sB2[o];
#pragma unroll
            for (int j = 0; j < 4; ++j) {
                float val = fmaxf(acc2[i][j][r] + bias, 0.f);
                zc0[j] += val * w3a;
                zc1[j] += val * w3b;
            }
        }
    }
    // reduce across lane quads (q): lanes {n, n+16, n+32, n+48} share the same row
#pragma unroll
    for (int j = 0; j < 4; ++j) {
        zc0[j] += __shfl_xor(zc0[j], 16, 64);
        zc0[j] += __shfl_xor(zc0[j], 32, 64);
        zc1[j] += __shfl_xor(zc1[j], 16, 64);
        zc1[j] += __shfl_xor(zc1[j], 32, 64);
    }
    // combine the two wave_m halves via LDS (write phase then add phase)
    if (wm == 0 && q == 0) {
#pragma unroll
        for (int j = 0; j < 4; ++j) {
            int row = wn + j * 16 + ln15;
            zbuf[row][0] = zc0[j];
            zbuf[row][1] = zc1[j];
        }
    }
    __syncthreads();
    if (wm == 64 && q == 0) {
#pragma unroll
        for (int j = 0; j < 4; ++j) {
            int row = wn + j * 16 + ln15;
            zbuf[row][0] += zc0[j];
            zbuf[row][1] += zc1[j];
        }
    }
    __syncthreads();
    {
        int row = tid >> 1, l = tid & 1;
        float vz = zbuf[row][l] + eb3[e * 2 + l];
        chart[(size_t)e * 65536 + (size_t)(rb * 128 + row) * 2 + l] = vz;
    }
}

// ---------------- final z = sum_e weights * chart ------------------
__global__ void z_final(const float* __restrict__ w, const float* __restrict__ chart,
                        float* __restrict__ z) {
    int row = blockIdx.x * 256 + threadIdx.x;
    float z0 = 0.f, z1 = 0.f;
#pragma unroll
    for (int e = 0; e < 10; ++e) {
        float we = w[(size_t)row * 10 + e];
        float2 c = *(const float2*)(&chart[(size_t)e * 65536 + (size_t)row * 2]);
        z0 += we * c.x;
        z1 += we * c.y;
    }
    float2 o; o.x = z0; o.y = z1;
    *(float2*)(&z[(size_t)row * 2]) = o;
}

extern "C" void kernel_launch(void* const* d_in, const int* in_sizes, int n_in,
                              void* d_out, int out_size, void* d_ws, size_t ws_size,
                              hipStream_t stream) {
    const float* x = (const float*)d_in[0];
    const float* u = (const float*)d_in[1];
    const float* rw1 = (const float*)d_in[2];
    const float* rb1 = (const float*)d_in[3];
    const float* rw2 = (const float*)d_in[4];
    const float* rb2 = (const float*)d_in[5];
    const float* rw3 = (const float*)d_in[6];
    const float* rb3 = (const float*)d_in[7];
    const float* ew1 = (const float*)d_in[8];
    const float* eb1 = (const float*)d_in[9];
    const float* ew2 = (const float*)d_in[10];
    const float* eb2 = (const float*)d_in[11];
    const float* ew3 = (const float*)d_in[12];
    const float* eb3 = (const float*)d_in[13];
    float* out = (float*)d_out;

    // workspace layout (bf16 elems), all 16B-aligned
    ushort_t* x16  = (ushort_t*)d_ws;            // 32768*512  = 16,777,216
    ushort_t* ew1t = x16 + 16777216;             // 10*128*512 =    655,360
    ushort_t* ew2t = ew1t + 655360;              // 10*128*128 =    163,840
    ushort_t* rw1t = ew2t + 163840;              // 256*512    =    131,072
    ushort_t* rw2t = rw1t + 131072;              // 128*256    =     32,768
    ushort_t* hr1  = rw2t + 32768;               // 32768*256  =  8,388,608
    ushort_t* hr2  = hr1 + 8388608;              // 32768*128  =  4,194,304
    // total ~60.7 MB

    convert_bf16<<<16384, 256, 0, stream>>>(x, x16, 16777216 / 4);
    transpose_bf16<<<2560, 256, 0, stream>>>(ew1, ew1t, 512, 128, 655360);
    transpose_bf16<<<640, 256, 0, stream>>>(ew2, ew2t, 128, 128, 163840);
    transpose_bf16<<<512, 256, 0, stream>>>(rw1, rw1t, 512, 256, 131072);
    transpose_bf16<<<128, 256, 0, stream>>>(rw2, rw2t, 256, 128, 32768);

    // router: x -> 256 -> 128, then logits + gumbel softmax -> weights
    gemm_rt<<<dim3(256, 2), 256, 0, stream>>>(x16, rw1t, rb1, hr1, 512, 256);
    gemm_rt<<<dim3(256, 1), 256, 0, stream>>>(hr1, rw2t, rb2, hr2, 256, 128);
    router_tail<<<128, 256, 0, stream>>>(hr2, rw3, rb3, u, out + 65536);

    // experts: fused 3-layer stack, writes chart_outputs [E][B][L]
    expert_fused<<<2560, 256, 0, stream>>>(x16, ew1t, ew2t, eb1, eb2, ew3, eb3,
                                           out + 393216);

    // z = sum_e weights[b,e] * chart[e,b,:]
    z_final<<<128, 256, 0, stream>>>(out + 65536, out + 393216, out);
}

// Round 2
// 228.599 us; speedup vs baseline: 1.1730x; 1.1730x over previous
//
#include <hip/hip_runtime.h>
#include <stdint.h>

typedef __bf16 bf16x8 __attribute__((ext_vector_type(8)));
typedef float floatx4 __attribute__((ext_vector_type(4)));
typedef unsigned short ushort_t;

__device__ __forceinline__ ushort_t bf16rne(float f) {
    union { float f; unsigned u; } v; v.f = f;
    return (ushort_t)((v.u + 0x7fffu + ((v.u >> 16) & 1u)) >> 16);
}

// async global->LDS, 16B per lane; LDS dest = base + lane*16 (wave-uniform base)
__device__ __forceinline__ void gl_lds16(const ushort_t* g, ushort_t* l) {
    __builtin_amdgcn_global_load_lds(
        (const __attribute__((address_space(1))) unsigned int*)g,
        (__attribute__((address_space(3))) unsigned int*)l, 16, 0, 0);
}

// ---------------- prep: convert x + 4 weight transposes, one launch ----------
__device__ __forceinline__ void transpose_body(const float* __restrict__ in,
                                               ushort_t* __restrict__ outp,
                                               int idx, int K, int N, int total) {
    if (idx >= total) return;
    int kn = K * N;
    int e = idx / kn;
    int r = idx - e * kn;
    int n = r / K;
    int k = r - n * K;
    outp[idx] = bf16rne(in[e * kn + k * N + n]);
}

__global__ void prep(const float* __restrict__ x, ushort_t* __restrict__ x16,
                     const float* __restrict__ ew1, ushort_t* __restrict__ ew1t,
                     const float* __restrict__ ew2, ushort_t* __restrict__ ew2t,
                     const float* __restrict__ rw1, ushort_t* __restrict__ rw1t,
                     const float* __restrict__ rw2, ushort_t* __restrict__ rw2t) {
    int b = blockIdx.x, tid = threadIdx.x;
    if (b < 16384) {
        int i = b * 256 + tid;   // 16,777,216/4 elems
        float4 f = ((const float4*)x)[i];
        union { ushort_t s[4]; uint2 v; } pk;
        pk.s[0] = bf16rne(f.x); pk.s[1] = bf16rne(f.y);
        pk.s[2] = bf16rne(f.z); pk.s[3] = bf16rne(f.w);
        ((uint2*)x16)[i] = pk.v;
    } else if (b < 18944) {
        transpose_body(ew1, ew1t, (b - 16384) * 256 + tid, 512, 128, 655360);
    } else if (b < 19584) {
        transpose_body(ew2, ew2t, (b - 18944) * 256 + tid, 128, 128, 163840);
    } else if (b < 20096) {
        transpose_body(rw1, rw1t, (b - 19584) * 256 + tid, 512, 256, 131072);
    } else {
        transpose_body(rw2, rw2t, (b - 20096) * 256 + tid, 256, 128, 32768);
    }
}

// ---------------- router layer 1: hr1 = relu(x @ rw1 + rb1) ------------------
// A = rw1t [256 n][512 k], B = x16 [row][512]; out row-major bf16 [row][256]
__global__ __launch_bounds__(256, 4)
void router_l1(const ushort_t* __restrict__ x16, const ushort_t* __restrict__ rw1t,
               const float* __restrict__ rb1, ushort_t* __restrict__ hr1) {
    __shared__ alignas(16) ushort_t sX[4096];   // [seg(8)][lane(64)][8]
    __shared__ alignas(16) ushort_t sW[4096];
    __shared__ float sBias[128];

    const int tid = threadIdx.x;
    const int rb = blockIdx.x, nb = blockIdx.y;
    const int wave = tid >> 6, lane = tid & 63;
    const int ln15 = lane & 15, q = lane >> 4;
    const int wm = (wave & 1) * 64, wn = (wave >> 1) * 64;
    const int mhalf = wm >> 6, nhalf = wn >> 6;

    if (tid < 128) sBias[tid] = rb1[nb * 128 + tid];

    const ushort_t* xblk = x16 + (size_t)rb * 128 * 512;
    const ushort_t* wbase = rw1t + (size_t)nb * 128 * 512;

    const int s0 = wave, s1 = wave + 4;
    const int srow0 = (wave * 16) + (lane >> 2);          // half 0
    const int srow1 = 64 + (wave * 16) + (lane >> 2);     // half 1
    const int scol = (lane & 3) * 8;

    floatx4 acc[4][4];
#pragma unroll
    for (int i = 0; i < 4; ++i)
#pragma unroll
        for (int j = 0; j < 4; ++j) acc[i][j] = (floatx4){0.f, 0.f, 0.f, 0.f};

    for (int k0 = 0; k0 < 512; k0 += 32) {
        __syncthreads();
        gl_lds16(xblk + (size_t)srow0 * 512 + k0 + scol, &sX[s0 * 512]);
        gl_lds16(xblk + (size_t)srow1 * 512 + k0 + scol, &sX[s1 * 512]);
        gl_lds16(wbase + (size_t)srow0 * 512 + k0 + scol, &sW[s0 * 512]);
        gl_lds16(wbase + (size_t)srow1 * 512 + k0 + scol, &sW[s1 * 512]);
        __syncthreads();
        bf16x8 a[4], b[4];
#pragma unroll
        for (int t = 0; t < 4; ++t) a[t] = *(const bf16x8*)(&sW[(mhalf * 4 + t) * 512 + ln15 * 32 + q * 8]);
#pragma unroll
        for (int t = 0; t < 4; ++t) b[t] = *(const bf16x8*)(&sX[(nhalf * 4 + t) * 512 + ln15 * 32 + q * 8]);
#pragma unroll
        for (int i = 0; i < 4; ++i)
#pragma unroll
            for (int j = 0; j < 4; ++j)
                acc[i][j] = __builtin_amdgcn_mfma_f32_16x16x32_bf16(a[i], b[j], acc[i][j], 0, 0, 0);
    }

    const int rbase = rb * 128;
#pragma unroll
    for (int i = 0; i < 4; ++i) {
        int n0 = wm + i * 16 + q * 4;
#pragma unroll
        for (int j = 0; j < 4; ++j) {
            int row = wn + j * 16 + ln15;
            union { ushort_t s[4]; uint2 v; } pk;
#pragma unroll
            for (int r = 0; r < 4; ++r)
                pk.s[r] = bf16rne(fmaxf(acc[i][j][r] + sBias[n0 + r], 0.f));
            *(uint2*)(&hr1[(size_t)(rbase + row) * 256 + nb * 128 + n0]) = pk.v;
        }
    }
}

// ------- router layer 2 fused: h2 = relu(hr1@rw2+rb2); logits=h2@rw3+rb3; ----
// ------- gumbel softmax -> weights; also zeros z --------------------------------
__global__ __launch_bounds__(256, 2)
void router2(const ushort_t* __restrict__ hr1, const ushort_t* __restrict__ rw2t,
             const float* __restrict__ rb2, const float* __restrict__ rw3,
             const float* __restrict__ rb3, const float* __restrict__ u,
             float* __restrict__ wts, float* __restrict__ z) {
    __shared__ alignas(16) ushort_t sA[4096];
    __shared__ alignas(16) ushort_t sB[4096];
    __shared__ float sw3[1280];
    __shared__ float sBias[128];
    __shared__ float lgbuf[128][10];

    const int tid = threadIdx.x;
    const int rb = blockIdx.x;
    const int wave = tid >> 6, lane = tid & 63;
    const int ln15 = lane & 15, q = lane >> 4;
    const int wm = (wave & 1) * 64, wn = (wave >> 1) * 64;
    const int mhalf = wm >> 6, nhalf = wn >> 6;

    for (int i = tid; i < 1280; i += 256) sw3[i] = rw3[i];
    if (tid < 128) sBias[tid] = rb2[tid];

    const ushort_t* brow = hr1 + (size_t)rb * 128 * 256;
    const int s0 = wave, s1 = wave + 4;
    const int srow0 = (wave * 16) + (lane >> 2);
    const int srow1 = 64 + (wave * 16) + (lane >> 2);
    const int scol = (lane & 3) * 8;

    floatx4 acc2[4][4];
#pragma unroll
    for (int i = 0; i < 4; ++i)
#pragma unroll
        for (int j = 0; j < 4; ++j) acc2[i][j] = (floatx4){0.f, 0.f, 0.f, 0.f};

    for (int k0 = 0; k0 < 256; k0 += 32) {
        __syncthreads();
        gl_lds16(rw2t + (size_t)srow0 * 256 + k0 + scol, &sA[s0 * 512]);
        gl_lds16(rw2t + (size_t)srow1 * 256 + k0 + scol, &sA[s1 * 512]);
        gl_lds16(brow + (size_t)srow0 * 256 + k0 + scol, &sB[s0 * 512]);
        gl_lds16(brow + (size_t)srow1 * 256 + k0 + scol, &sB[s1 * 512]);
        __syncthreads();
        bf16x8 a[4], b[4];
#pragma unroll
        for (int t = 0; t < 4; ++t) a[t] = *(const bf16x8*)(&sA[(mhalf * 4 + t) * 512 + ln15 * 32 + q * 8]);
#pragma unroll
        for (int t = 0; t < 4; ++t) b[t] = *(const bf16x8*)(&sB[(nhalf * 4 + t) * 512 + ln15 * 32 + q * 8]);
#pragma unroll
        for (int i = 0; i < 4; ++i)
#pragma unroll
            for (int j = 0; j < 4; ++j)
                acc2[i][j] = __builtin_amdgcn_mfma_f32_16x16x32_bf16(a[i], b[j], acc2[i][j], 0, 0, 0);
    }

    // partial logits: lg[j][e] over this lane's h values
    float lg[4][10];
#pragma unroll
    for (int j = 0; j < 4; ++j)
#pragma unroll
        for (int ee = 0; ee < 10; ++ee) lg[j][ee] = 0.f;
#pragma unroll
    for (int i = 0; i < 4; ++i) {
#pragma unroll
        for (int r = 0; r < 4; ++r) {
            int n = wm + i * 16 + q * 4 + r;
            float bias = sBias[n];
            const float* w3r = &sw3[n * 10];
#pragma unroll
            for (int j = 0; j < 4; ++j) {
                float val = fmaxf(acc2[i][j][r] + bias, 0.f);
#pragma unroll
                for (int ee = 0; ee < 10; ++ee) lg[j][ee] += val * w3r[ee];
            }
        }
    }
#pragma unroll
    for (int j = 0; j < 4; ++j)
#pragma unroll
        for (int ee = 0; ee < 10; ++ee) {
            lg[j][ee] += __shfl_xor(lg[j][ee], 16, 64);
            lg[j][ee] += __shfl_xor(lg[j][ee], 32, 64);
        }
    if (wm == 0 && q == 0) {
#pragma unroll
        for (int j = 0; j < 4; ++j) {
            int row = wn + 16 * j + ln15;
#pragma unroll
            for (int ee = 0; ee < 10; ++ee) lgbuf[row][ee] = lg[j][ee];
        }
    }
    __syncthreads();
    if (wm == 64 && q == 0) {
#pragma unroll
        for (int j = 0; j < 4; ++j) {
            int row = wn + 16 * j + ln15;
#pragma unroll
            for (int ee = 0; ee < 10; ++ee) lgbuf[row][ee] += lg[j][ee];
        }
    }
    __syncthreads();
    if (tid < 128) {
        int grow = rb * 128 + tid;
        float v[10], mx = -1e30f;
#pragma unroll
        for (int ee = 0; ee < 10; ++ee) {
            float uu = u[(size_t)grow * 10 + ee];
            uu = fminf(fmaxf(uu, 1e-10f), 1.0f);
            float g = -logf(-logf(uu) + 1e-10f);
            v[ee] = (lgbuf[tid][ee] + rb3[ee] + g) * (1.0f / 3.0f);
            mx = fmaxf(mx, v[ee]);
        }
        float s = 0.f;
#pragma unroll
        for (int ee = 0; ee < 10; ++ee) { v[ee] = expf(v[ee] - mx); s += v[ee]; }
        float inv = 1.0f / s;
#pragma unroll
        for (int ee = 0; ee < 10; ++ee) wts[(size_t)grow * 10 + ee] = v[ee] * inv;
    }
    z[rb * 256 + tid] = 0.f;   // zero z for expert atomics (256*256 = 65536)
}

// --------- fused expert stack: relu(x@W1) -> relu(@W2) -> @W3, + z atomics ---
__global__ __launch_bounds__(256, 3)
void expert_fused(const ushort_t* __restrict__ x16, const ushort_t* __restrict__ ew1t,
                  const ushort_t* __restrict__ ew2t, const float* __restrict__ eb1,
                  const float* __restrict__ eb2, const float* __restrict__ ew3,
                  const float* __restrict__ eb3, const float* __restrict__ wts,
                  float* __restrict__ chart, float* __restrict__ z) {
    __shared__ alignas(16) ushort_t sX[4096];    // per k-step x frags, lane order
    __shared__ alignas(16) ushort_t sW[4096];    // per k-step W1/W2 frags
    __shared__ alignas(16) ushort_t sH1[16384];  // h1, GEMM2-fragment order
    __shared__ float sB1[128];
    __shared__ float sB2[128];
    __shared__ float sW3[256];
    __shared__ float zbuf[128][2];

    const int tid = threadIdx.x;
    // XCD swizzle: all 10 experts of one rb land on the same XCD for x-tile L2 reuse
    const int id = blockIdx.x;
    const int xcd = id & 7, local = id >> 3;
    const int e = local % 10;
    const int rb = xcd * 32 + local / 10;

    const int wave = tid >> 6, lane = tid & 63;
    const int ln15 = lane & 15, q = lane >> 4;
    const int wm = (wave & 1) * 64, wn = (wave >> 1) * 64;
    const int mhalf = wm >> 6, nhalf = wn >> 6;

    if (tid < 128) sB1[tid] = eb1[e * 128 + tid];
    else sB2[tid - 128] = eb2[e * 128 + (tid - 128)];
    sW3[tid] = ew3[e * 256 + tid];

    const ushort_t* xblk = x16 + (size_t)rb * 128 * 512;
    const ushort_t* w1 = ew1t + (size_t)e * 128 * 512;
    const ushort_t* w2 = ew2t + (size_t)e * 128 * 128;

    const int s0 = wave, s1 = wave + 4;
    const int srow0 = (wave * 16) + (lane >> 2);
    const int srow1 = 64 + (wave * 16) + (lane >> 2);
    const int scol = (lane & 3) * 8;

    // ---- GEMM1: h1^T = W1^T · x^T ----
    {
        floatx4 acc[4][4];
#pragma unroll
        for (int i = 0; i < 4; ++i)
#pragma unroll
            for (int j = 0; j < 4; ++j) acc[i][j] = (floatx4){0.f, 0.f, 0.f, 0.f};

        for (int k0 = 0; k0 < 512; k0 += 32) {
            __syncthreads();
            gl_lds16(xblk + (size_t)srow0 * 512 + k0 + scol, &sX[s0 * 512]);
            gl_lds16(xblk + (size_t)srow1 * 512 + k0 + scol, &sX[s1 * 512]);
            gl_lds16(w1 + (size_t)srow0 * 512 + k0 + scol, &sW[s0 * 512]);
            gl_lds16(w1 + (size_t)srow1 * 512 + k0 + scol, &sW[s1 * 512]);
            __syncthreads();
            bf16x8 a[4], b[4];
#pragma unroll
            for (int t = 0; t < 4; ++t) a[t] = *(const bf16x8*)(&sW[(mhalf * 4 + t) * 512 + ln15 * 32 + q * 8]);
#pragma unroll
            for (int t = 0; t < 4; ++t) b[t] = *(const bf16x8*)(&sX[(nhalf * 4 + t) * 512 + ln15 * 32 + q * 8]);
#pragma unroll
            for (int i = 0; i < 4; ++i)
#pragma unroll
                for (int j = 0; j < 4; ++j)
                    acc[i][j] = __builtin_amdgcn_mfma_f32_16x16x32_bf16(a[i], b[j], acc[i][j], 0, 0, 0);
        }

        // relu(+bias) -> sH1 in GEMM2-fragment order:
        // offset = half*8192 + ks*2048 + t*512 + ln15*32 + (h&31)
        // write: half=wn>>6, t=j, ln15; h = wm+16i+4q+r -> ks = mhalf*2+(i>>1), h&31 = 16*(i&1)+4q
#pragma unroll
        for (int i = 0; i < 4; ++i) {
            int ks = mhalf * 2 + (i >> 1);
            int hlow = 16 * (i & 1) + 4 * q;
            int h0 = wm + i * 16 + q * 4;
#pragma unroll
            for (int j = 0; j < 4; ++j) {
                union { ushort_t s[4]; uint2 v; } pk;
#pragma unroll
                for (int r = 0; r < 4; ++r)
                    pk.s[r] = bf16rne(fmaxf(acc[i][j][r] + sB1[h0 + r], 0.f));
                *(uint2*)(&sH1[nhalf * 8192 + ks * 2048 + j * 512 + ln15 * 32 + hlow]) = pk.v;
            }
        }
    }

    // ---- GEMM2: h2^T = W2^T · h1^T ----
    floatx4 acc2[4][4];
#pragma unroll
    for (int i = 0; i < 4; ++i)
#pragma unroll
        for (int j = 0; j < 4; ++j) acc2[i][j] = (floatx4){0.f, 0.f, 0.f, 0.f};

    for (int k0 = 0; k0 < 128; k0 += 32) {
        __syncthreads();   // sH1 visibility (1st iter) + sW reuse guard
        gl_lds16(w2 + (size_t)srow0 * 128 + k0 + scol, &sW[s0 * 512]);
        gl_lds16(w2 + (size_t)srow1 * 128 + k0 + scol, &sW[s1 * 512]);
        __syncthreads();
        bf16x8 a[4], b[4];
#pragma unroll
        for (int t = 0; t < 4; ++t) a[t] = *(const bf16x8*)(&sW[(mhalf * 4 + t) * 512 + ln15 * 32 + q * 8]);
#pragma unroll
        for (int t = 0; t < 4; ++t) b[t] = *(const bf16x8*)(&sH1[nhalf * 8192 + (k0 >> 5) * 2048 + t * 512 + ln15 * 32 + q * 8]);
#pragma unroll
        for (int i = 0; i < 4; ++i)
#pragma unroll
            for (int j = 0; j < 4; ++j)
                acc2[i][j] = __builtin_amdgcn_mfma_f32_16x16x32_bf16(a[i], b[j], acc2[i][j], 0, 0, 0);
    }

    // ---- fused GEMM3 (L=2): zc[row][l] = sum_o relu(h2+b2)*w3[o][l] ----
    float zc0[4] = {0.f, 0.f, 0.f, 0.f}, zc1[4] = {0.f, 0.f, 0.f, 0.f};
#pragma unroll
    for (int i = 0; i < 4; ++i) {
        int o0 = wm + i * 16 + q * 4;
#pragma unroll
        for (int r = 0; r < 4; ++r) {
            int o = o0 + r;
            float w3a = sW3[2 * o], w3b = sW3[2 * o + 1];
            float bias = sB2[o];
#pragma unroll
            for (int j = 0; j < 4; ++j) {
                float val = fmaxf(acc2[i][j][r] + bias, 0.f);
                zc0[j] += val * w3a;
                zc1[j] += val * w3b;
            }
        }
    }
#pragma unroll
    for (int j = 0; j < 4; ++j) {
        zc0[j] += __shfl_xor(zc0[j], 16, 64);
        zc0[j] += __shfl_xor(zc0[j], 32, 64);
        zc1[j] += __shfl_xor(zc1[j], 16, 64);
        zc1[j] += __shfl_xor(zc1[j], 32, 64);
    }
    if (wm == 0 && q == 0) {
#pragma unroll
        for (int j = 0; j < 4; ++j) {
            int row = wn + j * 16 + ln15;
            zbuf[row][0] = zc0[j];
            zbuf[row][1] = zc1[j];
        }
    }
    __syncthreads();
    if (wm == 64 && q == 0) {
#pragma unroll
        for (int j = 0; j < 4; ++j) {
            int row = wn + j * 16 + ln15;
            zbuf[row][0] += zc0[j];
            zbuf[row][1] += zc1[j];
        }
    }
    __syncthreads();
    {
        int row = tid >> 1, l = tid & 1;
        int grow = rb * 128 + row;
        float vz = zbuf[row][l] + eb3[e * 2 + l];
        chart[(size_t)e * 65536 + (size_t)grow * 2 + l] = vz;
        atomicAdd(&z[(size_t)grow * 2 + l], wts[(size_t)grow * 10 + e] * vz);
    }
}

extern "C" void kernel_launch(void* const* d_in, const int* in_sizes, int n_in,
                              void* d_out, int out_size, void* d_ws, size_t ws_size,
                              hipStream_t stream) {
    const float* x = (const float*)d_in[0];
    const float* u = (const float*)d_in[1];
    const float* rw1 = (const float*)d_in[2];
    const float* rb1 = (const float*)d_in[3];
    const float* rw2 = (const float*)d_in[4];
    const float* rb2 = (const float*)d_in[5];
    const float* rw3 = (const float*)d_in[6];
    const float* rb3 = (const float*)d_in[7];
    const float* ew1 = (const float*)d_in[8];
    const float* eb1 = (const float*)d_in[9];
    const float* ew2 = (const float*)d_in[10];
    const float* eb2 = (const float*)d_in[11];
    const float* ew3 = (const float*)d_in[12];
    const float* eb3 = (const float*)d_in[13];
    float* out = (float*)d_out;
    float* z = out;                 // [32768, 2]
    float* wts = out + 65536;       // [32768, 10]
    float* chart = out + 393216;    // [10, 32768, 2]

    // workspace layout (bf16 elems), all 16B-aligned
    ushort_t* x16  = (ushort_t*)d_ws;            // 32768*512  = 16,777,216
    ushort_t* ew1t = x16 + 16777216;             // 10*128*512 =    655,360
    ushort_t* ew2t = ew1t + 655360;              // 10*128*128 =    163,840
    ushort_t* rw1t = ew2t + 163840;              // 256*512    =    131,072
    ushort_t* rw2t = rw1t + 131072;              // 128*256    =     32,768
    ushort_t* hr1  = rw2t + 32768;               // 32768*256  =  8,388,608

    prep<<<20224, 256, 0, stream>>>(x, x16, ew1, ew1t, ew2, ew2t, rw1, rw1t, rw2, rw2t);

    router_l1<<<dim3(256, 2), 256, 0, stream>>>(x16, rw1t, rb1, hr1);
    router2<<<256, 256, 0, stream>>>(hr1, rw2t, rb2, rw3, rb3, u, wts, z);

    expert_fused<<<2560, 256, 0, stream>>>(x16, ew1t, ew2t, eb1, eb2, ew3, eb3,
                                           wts, chart, z);
}